// Round 3
// baseline (1016.859 us; speedup 1.0000x reference)
//
#include <hip/hip_runtime.h>
#include <hip/hip_bf16.h>

// Problem constants
#define DMODEL 1024
#define DIN    2048
#define NH     32
#define HD     64
#define DS     64
#define LSEQ   1024
#define BB     2
#define DTOT   5312           // 2*DIN + 2*64 + 32 + 1024 + 32
#define ROWS   (BB*LSEQ)      // 2048
// column offsets inside zxbcdt
#define OFF_Z   0
#define OFF_X   2048
#define OFF_BR  4096
#define OFF_CR  4160
#define OFF_DT  4224
#define OFF_TH  4256
#define OFF_LAM 5280

// ---------------------------------------------------------------------------
// GEMM: C[M][N] = A[M][K] * B[N][K]^T   (both row-major over K)
// 128x128 tile, BK=16, 256 threads, 8x8 per thread. fp32 (no fp32 MFMA on CDNA4).
// ---------------------------------------------------------------------------
#define BM 128
#define BN 128
#define BK 16
#define LDT 132   // padded LDS leading dim (132%4==0 keeps b128 alignment, breaks bank collisions)

__global__ __launch_bounds__(256) void gemm_nt(const float* __restrict__ A,
                                               const float* __restrict__ B,
                                               float* __restrict__ C,
                                               int M, int N, int K) {
    __shared__ float As[BK][LDT];
    __shared__ float Bs[BK][LDT];
    const int tid = threadIdx.x;
    const int tx = tid & 15, ty = tid >> 4;
    const int m0 = blockIdx.y * BM, n0 = blockIdx.x * BN;

    float acc[8][8] = {};

    const int r0 = tid >> 2;            // 0..63
    const int r1 = r0 + 64;             // 64..127
    const int kq = (tid & 3) << 2;      // 0,4,8,12

    for (int k0 = 0; k0 < K; k0 += BK) {
        const float4 va0 = *(const float4*)(A + (size_t)(m0 + r0) * K + k0 + kq);
        const float4 va1 = *(const float4*)(A + (size_t)(m0 + r1) * K + k0 + kq);
        const int nb0 = n0 + r0, nb1 = n0 + r1;
        const float4 vb0 = (nb0 < N) ? *(const float4*)(B + (size_t)nb0 * K + k0 + kq)
                                     : make_float4(0.f, 0.f, 0.f, 0.f);
        const float4 vb1 = (nb1 < N) ? *(const float4*)(B + (size_t)nb1 * K + k0 + kq)
                                     : make_float4(0.f, 0.f, 0.f, 0.f);
        __syncthreads();   // previous compute done before overwriting LDS
        As[kq + 0][r0] = va0.x; As[kq + 1][r0] = va0.y; As[kq + 2][r0] = va0.z; As[kq + 3][r0] = va0.w;
        As[kq + 0][r1] = va1.x; As[kq + 1][r1] = va1.y; As[kq + 2][r1] = va1.z; As[kq + 3][r1] = va1.w;
        Bs[kq + 0][r0] = vb0.x; Bs[kq + 1][r0] = vb0.y; Bs[kq + 2][r0] = vb0.z; Bs[kq + 3][r0] = vb0.w;
        Bs[kq + 0][r1] = vb1.x; Bs[kq + 1][r1] = vb1.y; Bs[kq + 2][r1] = vb1.z; Bs[kq + 3][r1] = vb1.w;
        __syncthreads();
        #pragma unroll
        for (int k = 0; k < BK; ++k) {
            const float4 a0 = *(const float4*)&As[k][ty * 4];
            const float4 a1 = *(const float4*)&As[k][64 + ty * 4];
            const float4 b0 = *(const float4*)&Bs[k][tx * 4];
            const float4 b1 = *(const float4*)&Bs[k][64 + tx * 4];
            const float av[8] = {a0.x, a0.y, a0.z, a0.w, a1.x, a1.y, a1.z, a1.w};
            const float bv[8] = {b0.x, b0.y, b0.z, b0.w, b1.x, b1.y, b1.z, b1.w};
            #pragma unroll
            for (int i = 0; i < 8; ++i)
                #pragma unroll
                for (int j = 0; j < 8; ++j)
                    acc[i][j] = fmaf(av[i], bv[j], acc[i][j]);
        }
        __syncthreads();
    }

    #pragma unroll
    for (int i = 0; i < 8; ++i) {
        const int m = m0 + ((i < 4) ? (ty * 4 + i) : (64 + ty * 4 + (i - 4)));
        const int n1 = n0 + tx * 4;
        const int n2 = n0 + 64 + tx * 4;
        if (n1 < N)
            *(float4*)(C + (size_t)m * N + n1) = make_float4(acc[i][0], acc[i][1], acc[i][2], acc[i][3]);
        if (n2 < N)
            *(float4*)(C + (size_t)m * N + n2) = make_float4(acc[i][4], acc[i][5], acc[i][6], acc[i][7]);
    }
}

// ---------------------------------------------------------------------------
// prep: per (b,l) row — RMS-norm Br/Cr (64 each), dt/alpha/beta/gamma (32 heads)
// one wave (64 threads) per row
// ---------------------------------------------------------------------------
__global__ __launch_bounds__(64) void prep_kernel(const float* __restrict__ zx,
        const float* __restrict__ dt_bias, const float* __restrict__ A_log,
        const float* __restrict__ B_norm_w, const float* __restrict__ C_norm_w,
        float* __restrict__ Bg, float* __restrict__ Cg,
        float* __restrict__ alpha, float* __restrict__ beta, float* __restrict__ gam) {
    const int bl = blockIdx.x;
    const int t  = threadIdx.x;
    const float* row = zx + (size_t)bl * DTOT;
    const float br = row[OFF_BR + t];
    const float cr = row[OFF_CR + t];
    float ssb = br * br, ssc = cr * cr;
    #pragma unroll
    for (int k = 1; k < 64; k <<= 1) { ssb += __shfl_xor(ssb, k); ssc += __shfl_xor(ssc, k); }
    const float scB = rsqrtf(ssb * (1.f / 64.f) + 1e-5f);
    const float scC = rsqrtf(ssc * (1.f / 64.f) + 1e-5f);
    Bg[(size_t)bl * 64 + t] = br * scB * B_norm_w[t];
    Cg[(size_t)bl * 64 + t] = cr * scC * C_norm_w[t];
    if (t < NH) {
        const float dtr = row[OFF_DT + t] + dt_bias[t];
        const float dt  = (dtr > 20.f) ? dtr : log1pf(expf(dtr));
        const float lamr = row[OFF_LAM + t];
        const float lam  = 1.f / (1.f + expf(-lamr));
        const float Ah   = -expf(A_log[t]);
        const float al   = expf(dt * Ah);
        alpha[(size_t)bl * NH + t] = al;
        beta [(size_t)bl * NH + t] = (1.f - lam) * dt * al;
        gam  [(size_t)bl * NH + t] = lam * dt;
    }
}

// ---------------------------------------------------------------------------
// cumsum of thr over L, per (b,h): 32 dims. Two-pass chunked scan, 8 L-chunks.
// th_cs layout: (B, L, NH*32) contiguous
// ---------------------------------------------------------------------------
__global__ __launch_bounds__(256) void cumsum_kernel(const float* __restrict__ zx,
                                                     float* __restrict__ th_cs) {
    const int bh = blockIdx.x;            // b*32 + h
    const int b = bh >> 5, h = bh & 31;
    const int d = threadIdx.x & 31, seg = threadIdx.x >> 5;   // 8 segs x 128 l's
    const float* base = zx + (size_t)b * LSEQ * DTOT + OFF_TH + h * 32 + d;
    float* out = th_cs + (size_t)b * LSEQ * 1024 + h * 32 + d;
    __shared__ float sums[8][33];
    const int l0 = seg * 128;
    float s = 0.f;
    #pragma unroll 4
    for (int i = 0; i < 128; ++i) s += base[(size_t)(l0 + i) * DTOT];
    sums[seg][d] = s;
    __syncthreads();
    float acc = 0.f;
    for (int s2 = 0; s2 < seg; ++s2) acc += sums[s2][d];
    #pragma unroll 4
    for (int i = 0; i < 128; ++i) {
        acc += base[(size_t)(l0 + i) * DTOT];
        out[(size_t)(l0 + i) * 1024] = acc;
    }
}

// ---------------------------------------------------------------------------
// rot: Bh/Ch = rot(broadcast(Bg/Cg)+bias) with angles th_cs. One thread per
// (b,l,h,j<32) handles both halves of both B and C.
// Brot/Crot layout: (B, NH, L, DS)  — scan-contiguous
// ---------------------------------------------------------------------------
__global__ __launch_bounds__(256) void rot_kernel(const float* __restrict__ th_cs,
        const float* __restrict__ Bg, const float* __restrict__ Cg,
        const float* __restrict__ B_bias, const float* __restrict__ C_bias,
        float* __restrict__ Brot, float* __restrict__ Crot) {
    const size_t idx = (size_t)blockIdx.x * 256 + threadIdx.x;  // over B*L*NH*32
    const int j = (int)(idx & 31);
    const int h = (int)((idx >> 5) & 31);
    const size_t bl = idx >> 10;          // b*1024 + l
    const int l = (int)(bl & (LSEQ - 1));
    const int b = (int)(bl >> 10);
    const float th = th_cs[idx];
    float s, c;
    sincosf(th, &s, &c);
    float v1 = Bg[bl * 64 + j]      + B_bias[h * 64 + j];
    float v2 = Bg[bl * 64 + 32 + j] + B_bias[h * 64 + 32 + j];
    const size_t ob = ((size_t)(b * NH + h) * LSEQ + l) * DS + j;
    Brot[ob]      = v1 * c - v2 * s;
    Brot[ob + 32] = v1 * s + v2 * c;
    v1 = Cg[bl * 64 + j]      + C_bias[h * 64 + j];
    v2 = Cg[bl * 64 + 32 + j] + C_bias[h * 64 + 32 + j];
    Crot[ob]      = v1 * c - v2 * s;
    Crot[ob + 32] = v1 * s + v2 * c;
}

// ---------------------------------------------------------------------------
// scan: block = (b, h, ptile of 16 HD rows). 256 threads: (pl 0..15, ng 0..15),
// thread holds 4 state elems (n = ng*4..+3). bx_prev is rank-1: keep x_prev,
// B_prev only. Depth-2 software pipeline on the per-step loads.
// ---------------------------------------------------------------------------
__global__ __launch_bounds__(256) void scan_kernel(const float* __restrict__ zx,
        const float* __restrict__ Brot, const float* __restrict__ Crot,
        const float* __restrict__ alpha, const float* __restrict__ beta,
        const float* __restrict__ gam, const float* __restrict__ Dp,
        float* __restrict__ yb) {
    const int blk = blockIdx.x;
    const int ptile = blk & 3, h = (blk >> 2) & 31, b = blk >> 7;
    const int tid = threadIdx.x;
    const int pl = tid >> 4, ng = tid & 15;
    const int p = ptile * 16 + pl;
    const int n0 = ng * 4;

    const float* Bbase = Brot + ((size_t)(b * NH + h) * LSEQ) * DS + n0;
    const float* Cbase = Crot + ((size_t)(b * NH + h) * LSEQ) * DS + n0;
    const float* xbase = zx + (size_t)b * LSEQ * DTOT + OFF_X + h * HD + p;
    const float* abase = alpha + (size_t)b * LSEQ * NH + h;
    const float* bbase = beta  + (size_t)b * LSEQ * NH + h;
    const float* gbase = gam   + (size_t)b * LSEQ * NH + h;
    const float Dh = Dp[h];
    float* ybase = yb + (size_t)b * LSEQ * DIN + h * HD + p;

    float hs0 = 0.f, hs1 = 0.f, hs2 = 0.f, hs3 = 0.f;
    float Bp0 = 0.f, Bp1 = 0.f, Bp2 = 0.f, Bp3 = 0.f;
    float xprev = 0.f;

#define LOADS(t, Bv, Cv, xv, av, bv, gv) {                       \
        const int _t = (t);                                      \
        Bv = *(const float4*)(Bbase + (size_t)_t * DS);          \
        Cv = *(const float4*)(Cbase + (size_t)_t * DS);          \
        xv = xbase[(size_t)_t * DTOT];                           \
        av = abase[(size_t)_t * NH];                             \
        bv = bbase[(size_t)_t * NH];                             \
        gv = gbase[(size_t)_t * NH]; }

    float4 B0v, C0v, B1v, C1v, B2v, C2v;
    float x0, a0, b0, g0, x1, a1, b1, g1, x2, a2, b2, g2;
    LOADS(0, B0v, C0v, x0, a0, b0, g0);
    LOADS(1, B1v, C1v, x1, a1, b1, g1);

    for (int t = 0; t < LSEQ; ++t) {
        int tp = t + 2; if (tp > LSEQ - 1) tp = LSEQ - 1;
        LOADS(tp, B2v, C2v, x2, a2, b2, g2);

        const float cp = b0 * xprev;
        const float cc = g0 * x0;
        float ys;
        hs0 = fmaf(a0, hs0, fmaf(cp, Bp0, cc * B0v.x)); ys  = C0v.x * hs0;
        hs1 = fmaf(a0, hs1, fmaf(cp, Bp1, cc * B0v.y)); ys += C0v.y * hs1;
        hs2 = fmaf(a0, hs2, fmaf(cp, Bp2, cc * B0v.z)); ys += C0v.z * hs2;
        hs3 = fmaf(a0, hs3, fmaf(cp, Bp3, cc * B0v.w)); ys += C0v.w * hs3;
        ys += __shfl_xor(ys, 1);
        ys += __shfl_xor(ys, 2);
        ys += __shfl_xor(ys, 4);
        ys += __shfl_xor(ys, 8);
        if (ng == 0) ybase[(size_t)t * DIN] = fmaf(Dh, x0, ys);

        Bp0 = B0v.x; Bp1 = B0v.y; Bp2 = B0v.z; Bp3 = B0v.w;
        xprev = x0;
        B0v = B1v; C0v = C1v; x0 = x1; a0 = a1; b0 = b1; g0 = g1;
        B1v = B2v; C1v = C2v; x1 = x2; a1 = a2; b1 = b2; g1 = g2;
    }
#undef LOADS
}

// ---------------------------------------------------------------------------
// gate + final RMS norm: g = y * silu(z); gn = rms(g) * norm_w
// one block per (b,l) row, 256 threads x 8 elems
// ---------------------------------------------------------------------------
__global__ __launch_bounds__(256) void gate_norm_kernel(const float* __restrict__ yb,
        const float* __restrict__ zx, const float* __restrict__ norm_w,
        float* __restrict__ gn) {
    const int bl = blockIdx.x;
    const int tid = threadIdx.x;
    const float* yrow = yb + (size_t)bl * DIN;
    const float* zrow = zx + (size_t)bl * DTOT + OFF_Z;
    float g[8];
    float ss = 0.f;
    #pragma unroll
    for (int i = 0; i < 8; ++i) {
        const int c = tid + i * 256;
        const float yv = yrow[c];
        const float zv = zrow[c];
        const float sg = 1.f / (1.f + expf(-zv));
        const float gv = yv * zv * sg;
        g[i] = gv;
        ss += gv * gv;
    }
    #pragma unroll
    for (int k = 1; k < 64; k <<= 1) ss += __shfl_xor(ss, k);
    __shared__ float wsum[4];
    if ((tid & 63) == 0) wsum[tid >> 6] = ss;
    __syncthreads();
    ss = wsum[0] + wsum[1] + wsum[2] + wsum[3];
    const float sc = rsqrtf(ss * (1.f / 2048.f) + 1e-5f);
    #pragma unroll
    for (int i = 0; i < 8; ++i) {
        const int c = tid + i * 256;
        gn[(size_t)bl * DIN + c] = g[i] * sc * norm_w[c];
    }
}

// ---------------------------------------------------------------------------
extern "C" void kernel_launch(void* const* d_in, const int* in_sizes, int n_in,
                              void* d_out, int out_size, void* d_ws, size_t ws_size,
                              hipStream_t stream) {
    const float* u          = (const float*)d_in[0];
    const float* in_proj_w  = (const float*)d_in[1];
    const float* dt_bias    = (const float*)d_in[2];
    const float* A_log      = (const float*)d_in[3];
    const float* Dp         = (const float*)d_in[4];
    const float* B_norm_w   = (const float*)d_in[5];
    const float* C_norm_w   = (const float*)d_in[6];
    const float* B_bias     = (const float*)d_in[7];
    const float* C_bias     = (const float*)d_in[8];
    const float* norm_w     = (const float*)d_in[9];
    const float* out_proj_w = (const float*)d_in[10];
    float* out = (float*)d_out;

    // workspace layout (floats); total ~104 MB
    float* p = (float*)d_ws;
    float* zx    = p; p += (size_t)ROWS * DTOT;   // 10,878,976
    float* th_cs = p; p += (size_t)ROWS * 1024;   //  2,097,152
    float* Brot  = p; p += (size_t)ROWS * 2048;   //  4,194,304
    float* Crot  = p; p += (size_t)ROWS * 2048;   //  4,194,304
    float* Bg    = p; p += (size_t)ROWS * 64;
    float* Cg    = p; p += (size_t)ROWS * 64;
    float* alpha = p; p += (size_t)ROWS * NH;
    float* beta  = p; p += (size_t)ROWS * NH;
    float* gam   = p; p += (size_t)ROWS * NH;
    float* yb    = p; p += (size_t)ROWS * 2048;
    float* gn    = Brot;   // reuse: Brot dead after scan

    // 1. zxbcdt = u @ in_proj_w^T    (M=2048, N=5312, K=1024)
    gemm_nt<<<dim3((DTOT + BN - 1) / BN, ROWS / BM), 256, 0, stream>>>(
        u, in_proj_w, zx, ROWS, DTOT, DMODEL);
    // 2. per-row prep
    prep_kernel<<<ROWS, 64, 0, stream>>>(zx, dt_bias, A_log, B_norm_w, C_norm_w,
                                         Bg, Cg, alpha, beta, gam);
    // 3. cumsum of theta over L
    cumsum_kernel<<<BB * NH, 256, 0, stream>>>(zx, th_cs);
    // 4. rotary on B/C
    rot_kernel<<<(ROWS * 1024) / 256, 256, 0, stream>>>(th_cs, Bg, Cg, B_bias, C_bias,
                                                        Brot, Crot);
    // 5. sequential scan over L
    scan_kernel<<<BB * NH * 4, 256, 0, stream>>>(zx, Brot, Crot, alpha, beta, gam, Dp, yb);
    // 6. gate + RMS norm
    gate_norm_kernel<<<ROWS, 256, 0, stream>>>(yb, zx, norm_w, gn);
    // 7. out = gn @ out_proj_w^T     (M=2048, N=1024, K=2048)
    gemm_nt<<<dim3(DMODEL / BN, ROWS / BM), 256, 0, stream>>>(
        gn, out_proj_w, out, ROWS, DMODEL, DIN);
}

// Round 4
// 815.688 us; speedup vs baseline: 1.2466x; 1.2466x over previous
//
#include <hip/hip_runtime.h>
#include <hip/hip_bf16.h>

// Problem constants
#define DMODEL 1024
#define DIN    2048
#define NH     32
#define HD     64
#define DS     64
#define LSEQ   1024
#define BB     2
#define DTOT   5312           // 2*DIN + 2*64 + 32 + 1024 + 32
#define ROWS   (BB*LSEQ)      // 2048
// column offsets inside zxbcdt
#define OFF_Z   0
#define OFF_X   2048
#define OFF_BR  4096
#define OFF_CR  4160
#define OFF_DT  4224
#define OFF_TH  4256
#define OFF_LAM 5280

// ---------------------------------------------------------------------------
// GEMM: C[M][N] = A[M][K] * B[N][K]^T   (both row-major over K)
// 128x128 tile, BK=16, 256 threads, 8x8 per thread. fp32 (no fp32 MFMA on CDNA4).
// ---------------------------------------------------------------------------
#define BM 128
#define BN 128
#define BK 16
#define LDT 132   // padded LDS leading dim

__global__ __launch_bounds__(256) void gemm_nt(const float* __restrict__ A,
                                               const float* __restrict__ B,
                                               float* __restrict__ C,
                                               int M, int N, int K) {
    __shared__ float As[BK][LDT];
    __shared__ float Bs[BK][LDT];
    const int tid = threadIdx.x;
    const int tx = tid & 15, ty = tid >> 4;
    const int m0 = blockIdx.y * BM, n0 = blockIdx.x * BN;

    float acc[8][8] = {};

    const int r0 = tid >> 2;            // 0..63
    const int r1 = r0 + 64;             // 64..127
    const int kq = (tid & 3) << 2;      // 0,4,8,12

    for (int k0 = 0; k0 < K; k0 += BK) {
        const float4 va0 = *(const float4*)(A + (size_t)(m0 + r0) * K + k0 + kq);
        const float4 va1 = *(const float4*)(A + (size_t)(m0 + r1) * K + k0 + kq);
        const int nb0 = n0 + r0, nb1 = n0 + r1;
        const float4 vb0 = (nb0 < N) ? *(const float4*)(B + (size_t)nb0 * K + k0 + kq)
                                     : make_float4(0.f, 0.f, 0.f, 0.f);
        const float4 vb1 = (nb1 < N) ? *(const float4*)(B + (size_t)nb1 * K + k0 + kq)
                                     : make_float4(0.f, 0.f, 0.f, 0.f);
        __syncthreads();   // previous compute done before overwriting LDS
        As[kq + 0][r0] = va0.x; As[kq + 1][r0] = va0.y; As[kq + 2][r0] = va0.z; As[kq + 3][r0] = va0.w;
        As[kq + 0][r1] = va1.x; As[kq + 1][r1] = va1.y; As[kq + 2][r1] = va1.z; As[kq + 3][r1] = va1.w;
        Bs[kq + 0][r0] = vb0.x; Bs[kq + 1][r0] = vb0.y; Bs[kq + 2][r0] = vb0.z; Bs[kq + 3][r0] = vb0.w;
        Bs[kq + 0][r1] = vb1.x; Bs[kq + 1][r1] = vb1.y; Bs[kq + 2][r1] = vb1.z; Bs[kq + 3][r1] = vb1.w;
        __syncthreads();
        #pragma unroll
        for (int k = 0; k < BK; ++k) {
            const float4 a0 = *(const float4*)&As[k][ty * 4];
            const float4 a1 = *(const float4*)&As[k][64 + ty * 4];
            const float4 b0 = *(const float4*)&Bs[k][tx * 4];
            const float4 b1 = *(const float4*)&Bs[k][64 + tx * 4];
            const float av[8] = {a0.x, a0.y, a0.z, a0.w, a1.x, a1.y, a1.z, a1.w};
            const float bv[8] = {b0.x, b0.y, b0.z, b0.w, b1.x, b1.y, b1.z, b1.w};
            #pragma unroll
            for (int i = 0; i < 8; ++i)
                #pragma unroll
                for (int j = 0; j < 8; ++j)
                    acc[i][j] = fmaf(av[i], bv[j], acc[i][j]);
        }
        __syncthreads();
    }

    #pragma unroll
    for (int i = 0; i < 8; ++i) {
        const int m = m0 + ((i < 4) ? (ty * 4 + i) : (64 + ty * 4 + (i - 4)));
        const int n1 = n0 + tx * 4;
        const int n2 = n0 + 64 + tx * 4;
        if (n1 < N)
            *(float4*)(C + (size_t)m * N + n1) = make_float4(acc[i][0], acc[i][1], acc[i][2], acc[i][3]);
        if (n2 < N)
            *(float4*)(C + (size_t)m * N + n2) = make_float4(acc[i][4], acc[i][5], acc[i][6], acc[i][7]);
    }
}

// ---------------------------------------------------------------------------
// prep: per (b,l) row — RMS-norm Br/Cr, dt/alpha/beta/gamma (32 heads).
// alpha/beta/gamma written TRANSPOSED to (b,h,l) so scan can bulk-stage them.
// ---------------------------------------------------------------------------
__global__ __launch_bounds__(64) void prep_kernel(const float* __restrict__ zx,
        const float* __restrict__ dt_bias, const float* __restrict__ A_log,
        const float* __restrict__ B_norm_w, const float* __restrict__ C_norm_w,
        float* __restrict__ Bg, float* __restrict__ Cg,
        float* __restrict__ aT, float* __restrict__ bT, float* __restrict__ gT) {
    const int bl = blockIdx.x;
    const int b = bl >> 10, l = bl & (LSEQ - 1);
    const int t  = threadIdx.x;
    const float* row = zx + (size_t)bl * DTOT;
    const float br = row[OFF_BR + t];
    const float cr = row[OFF_CR + t];
    float ssb = br * br, ssc = cr * cr;
    #pragma unroll
    for (int k = 1; k < 64; k <<= 1) { ssb += __shfl_xor(ssb, k); ssc += __shfl_xor(ssc, k); }
    const float scB = rsqrtf(ssb * (1.f / 64.f) + 1e-5f);
    const float scC = rsqrtf(ssc * (1.f / 64.f) + 1e-5f);
    Bg[(size_t)bl * 64 + t] = br * scB * B_norm_w[t];
    Cg[(size_t)bl * 64 + t] = cr * scC * C_norm_w[t];
    if (t < NH) {
        const float dtr = row[OFF_DT + t] + dt_bias[t];
        const float dt  = (dtr > 20.f) ? dtr : log1pf(expf(dtr));
        const float lamr = row[OFF_LAM + t];
        const float lam  = 1.f / (1.f + expf(-lamr));
        const float Ah   = -expf(A_log[t]);
        const float al   = expf(dt * Ah);
        const size_t o = ((size_t)b * NH + t) * LSEQ + l;
        aT[o] = al;
        bT[o] = (1.f - lam) * dt * al;
        gT[o] = lam * dt;
    }
}

// ---------------------------------------------------------------------------
// cumsum of thr over L, per (b,h): 32 dims.
// ---------------------------------------------------------------------------
__global__ __launch_bounds__(256) void cumsum_kernel(const float* __restrict__ zx,
                                                     float* __restrict__ th_cs) {
    const int bh = blockIdx.x;            // b*32 + h
    const int b = bh >> 5, h = bh & 31;
    const int d = threadIdx.x & 31, seg = threadIdx.x >> 5;   // 8 segs x 128 l's
    const float* base = zx + (size_t)b * LSEQ * DTOT + OFF_TH + h * 32 + d;
    float* out = th_cs + (size_t)b * LSEQ * 1024 + h * 32 + d;
    __shared__ float sums[8][33];
    const int l0 = seg * 128;
    float s = 0.f;
    #pragma unroll 4
    for (int i = 0; i < 128; ++i) s += base[(size_t)(l0 + i) * DTOT];
    sums[seg][d] = s;
    __syncthreads();
    float acc = 0.f;
    for (int s2 = 0; s2 < seg; ++s2) acc += sums[s2][d];
    #pragma unroll 4
    for (int i = 0; i < 128; ++i) {
        acc += base[(size_t)(l0 + i) * DTOT];
        out[(size_t)(l0 + i) * 1024] = acc;
    }
}

// ---------------------------------------------------------------------------
// rot: Bh/Ch = rot(broadcast(Bg/Cg)+bias). Brot/Crot layout (B,NH,L,DS).
// ---------------------------------------------------------------------------
__global__ __launch_bounds__(256) void rot_kernel(const float* __restrict__ th_cs,
        const float* __restrict__ Bg, const float* __restrict__ Cg,
        const float* __restrict__ B_bias, const float* __restrict__ C_bias,
        float* __restrict__ Brot, float* __restrict__ Crot) {
    const size_t idx = (size_t)blockIdx.x * 256 + threadIdx.x;  // over B*L*NH*32
    const int j = (int)(idx & 31);
    const int h = (int)((idx >> 5) & 31);
    const size_t bl = idx >> 10;          // b*1024 + l
    const int l = (int)(bl & (LSEQ - 1));
    const int b = (int)(bl >> 10);
    const float th = th_cs[idx];
    float s, c;
    sincosf(th, &s, &c);
    float v1 = Bg[bl * 64 + j]      + B_bias[h * 64 + j];
    float v2 = Bg[bl * 64 + 32 + j] + B_bias[h * 64 + 32 + j];
    const size_t ob = ((size_t)(b * NH + h) * LSEQ + l) * DS + j;
    Brot[ob]      = v1 * c - v2 * s;
    Brot[ob + 32] = v1 * s + v2 * c;
    v1 = Cg[bl * 64 + j]      + C_bias[h * 64 + j];
    v2 = Cg[bl * 64 + 32 + j] + C_bias[h * 64 + 32 + j];
    Crot[ob]      = v1 * c - v2 * s;
    Crot[ob + 32] = v1 * s + v2 * c;
}

// ---------------------------------------------------------------------------
// scan: block = (b, h, ptile of 16 HD rows). 256 threads: (pl 0..15, ng 0..15),
// thread holds 4 state elems. LDS chunked double-buffer staging (CH=32 steps):
// issue chunk ch+1 global loads right after the barrier, compute chunk ch from
// LDS (~1600 cyc ≫ load latency), ds_write + one barrier per chunk.
// ---------------------------------------------------------------------------
#define CH 32
#define NC (LSEQ / CH)

__global__ __launch_bounds__(256) void scan_kernel(const float* __restrict__ zx,
        const float* __restrict__ Brot, const float* __restrict__ Crot,
        const float* __restrict__ aT, const float* __restrict__ bT,
        const float* __restrict__ gT, const float* __restrict__ Dp,
        float* __restrict__ yb) {
    const int blk = blockIdx.x;
    const int ptile = blk & 3, h = (blk >> 2) & 31, b = blk >> 7;
    const int tid = threadIdx.x;
    const int pl = tid >> 4, ng = tid & 15;
    const int p = ptile * 16 + pl;
    const int n0 = ng * 4;

    __shared__ float Bsh[2][CH][DS];     // 16 KB
    __shared__ float Csh[2][CH][DS];     // 16 KB
    __shared__ float xsh[2][CH][16];     //  4 KB
    __shared__ float abg[2][3][CH];      //  0.75 KB

    const size_t bh = (size_t)b * NH + h;
    const float* Bbase = Brot + bh * LSEQ * DS;
    const float* Cbase = Crot + bh * LSEQ * DS;
    const float* abase = aT + bh * LSEQ;
    const float* bbase = bT + bh * LSEQ;
    const float* gbase = gT + bh * LSEQ;
    const float* xbase = zx + (size_t)b * LSEQ * DTOT + OFF_X + h * HD + ptile * 16;
    const float Dh = Dp[h];
    float* ybase = yb + (size_t)b * LSEQ * DIN + h * HD + p;

    // staging registers (issue-early / write-late)
    float4 rb0, rb1, rc0, rc1, rx;
    float rabg = 0.f;
    const int xs_s = tid >> 2, xs_q = (tid & 3) * 4;   // tid<128: step / col quad
    const int ab_arr = tid >> 5, ab_s = tid & 31;      // tid<96: array / step

#define STAGE_LOAD(chv) {                                                           \
        const int c0 = (chv) * CH;                                                  \
        rb0 = *(const float4*)(Bbase + (size_t)c0 * DS + tid * 8);                  \
        rb1 = *(const float4*)(Bbase + (size_t)c0 * DS + tid * 8 + 4);              \
        rc0 = *(const float4*)(Cbase + (size_t)c0 * DS + tid * 8);                  \
        rc1 = *(const float4*)(Cbase + (size_t)c0 * DS + tid * 8 + 4);              \
        if (tid < 128)                                                              \
            rx = *(const float4*)(xbase + (size_t)(c0 + xs_s) * DTOT + xs_q);       \
        if (tid < 96) {                                                             \
            const float* ab = (ab_arr == 0) ? abase : (ab_arr == 1) ? bbase : gbase;\
            rabg = ab[c0 + ab_s];                                                   \
        }                                                                           \
    }

#define STAGE_WRITE(cur) {                                                          \
        float* bf = &Bsh[cur][0][0]; float* cf = &Csh[cur][0][0];                   \
        *(float4*)(bf + tid * 8)     = rb0;  *(float4*)(bf + tid * 8 + 4) = rb1;    \
        *(float4*)(cf + tid * 8)     = rc0;  *(float4*)(cf + tid * 8 + 4) = rc1;    \
        if (tid < 128) *(float4*)(&xsh[cur][0][0] + tid * 4) = rx;                  \
        if (tid < 96) abg[cur][ab_arr][ab_s] = rabg;                                \
    }

    float hs0 = 0.f, hs1 = 0.f, hs2 = 0.f, hs3 = 0.f;
    float Bp0 = 0.f, Bp1 = 0.f, Bp2 = 0.f, Bp3 = 0.f;
    float xprev = 0.f;

    STAGE_LOAD(0);
    int cur = 0;
    for (int ch = 0; ch < NC; ++ch) {
        STAGE_WRITE(cur);
        __syncthreads();
        if (ch + 1 < NC) STAGE_LOAD(ch + 1);   // in flight across this chunk's compute
        const int t0 = ch * CH;
        #pragma unroll 4
        for (int s = 0; s < CH; ++s) {
            const float4 Bv = *(const float4*)&Bsh[cur][s][n0];
            const float4 Cv = *(const float4*)&Csh[cur][s][n0];
            const float xv = xsh[cur][s][pl];
            const float av = abg[cur][0][s];
            const float bv = abg[cur][1][s];
            const float gv = abg[cur][2][s];
            const float cp = bv * xprev;
            const float cc = gv * xv;
            float ys;
            hs0 = fmaf(av, hs0, fmaf(cp, Bp0, cc * Bv.x)); ys  = Cv.x * hs0;
            hs1 = fmaf(av, hs1, fmaf(cp, Bp1, cc * Bv.y)); ys += Cv.y * hs1;
            hs2 = fmaf(av, hs2, fmaf(cp, Bp2, cc * Bv.z)); ys += Cv.z * hs2;
            hs3 = fmaf(av, hs3, fmaf(cp, Bp3, cc * Bv.w)); ys += Cv.w * hs3;
            ys += __shfl_xor(ys, 1);
            ys += __shfl_xor(ys, 2);
            ys += __shfl_xor(ys, 4);
            ys += __shfl_xor(ys, 8);
            if (ng == 0) ybase[(size_t)(t0 + s) * DIN] = fmaf(Dh, xv, ys);
            Bp0 = Bv.x; Bp1 = Bv.y; Bp2 = Bv.z; Bp3 = Bv.w;
            xprev = xv;
        }
        cur ^= 1;
        // no second barrier needed: next STAGE_WRITE targets the other buffer,
        // and the per-iteration barrier prevents any wave from getting 2 ahead.
    }
#undef STAGE_LOAD
#undef STAGE_WRITE
}

// ---------------------------------------------------------------------------
// gate + final RMS norm: g = y * silu(z); gn = rms(g) * norm_w
// ---------------------------------------------------------------------------
__global__ __launch_bounds__(256) void gate_norm_kernel(const float* __restrict__ yb,
        const float* __restrict__ zx, const float* __restrict__ norm_w,
        float* __restrict__ gn) {
    const int bl = blockIdx.x;
    const int tid = threadIdx.x;
    const float* yrow = yb + (size_t)bl * DIN;
    const float* zrow = zx + (size_t)bl * DTOT + OFF_Z;
    float g[8];
    float ss = 0.f;
    #pragma unroll
    for (int i = 0; i < 8; ++i) {
        const int c = tid + i * 256;
        const float yv = yrow[c];
        const float zv = zrow[c];
        const float sg = 1.f / (1.f + expf(-zv));
        const float gv = yv * zv * sg;
        g[i] = gv;
        ss += gv * gv;
    }
    #pragma unroll
    for (int k = 1; k < 64; k <<= 1) ss += __shfl_xor(ss, k);
    __shared__ float wsum[4];
    if ((tid & 63) == 0) wsum[tid >> 6] = ss;
    __syncthreads();
    ss = wsum[0] + wsum[1] + wsum[2] + wsum[3];
    const float sc = rsqrtf(ss * (1.f / 2048.f) + 1e-5f);
    #pragma unroll
    for (int i = 0; i < 8; ++i) {
        const int c = tid + i * 256;
        gn[(size_t)bl * DIN + c] = g[i] * sc * norm_w[c];
    }
}

// ---------------------------------------------------------------------------
extern "C" void kernel_launch(void* const* d_in, const int* in_sizes, int n_in,
                              void* d_out, int out_size, void* d_ws, size_t ws_size,
                              hipStream_t stream) {
    const float* u          = (const float*)d_in[0];
    const float* in_proj_w  = (const float*)d_in[1];
    const float* dt_bias    = (const float*)d_in[2];
    const float* A_log      = (const float*)d_in[3];
    const float* Dp         = (const float*)d_in[4];
    const float* B_norm_w   = (const float*)d_in[5];
    const float* C_norm_w   = (const float*)d_in[6];
    const float* B_bias     = (const float*)d_in[7];
    const float* C_bias     = (const float*)d_in[8];
    const float* norm_w     = (const float*)d_in[9];
    const float* out_proj_w = (const float*)d_in[10];
    float* out = (float*)d_out;

    // workspace layout (floats); total ~104 MB
    float* p = (float*)d_ws;
    float* zx    = p; p += (size_t)ROWS * DTOT;   // 10,878,976
    float* th_cs = p; p += (size_t)ROWS * 1024;   //  2,097,152
    float* Brot  = p; p += (size_t)ROWS * 2048;   //  4,194,304
    float* Crot  = p; p += (size_t)ROWS * 2048;   //  4,194,304
    float* Bg    = p; p += (size_t)ROWS * 64;
    float* Cg    = p; p += (size_t)ROWS * 64;
    float* aT    = p; p += (size_t)ROWS * NH;     // (b,h,l) layout
    float* bT    = p; p += (size_t)ROWS * NH;
    float* gT    = p; p += (size_t)ROWS * NH;
    float* yb    = p; p += (size_t)ROWS * 2048;
    float* gn    = Brot;   // reuse: Brot dead after scan

    // 1. zxbcdt = u @ in_proj_w^T    (M=2048, N=5312, K=1024)
    gemm_nt<<<dim3((DTOT + BN - 1) / BN, ROWS / BM), 256, 0, stream>>>(
        u, in_proj_w, zx, ROWS, DTOT, DMODEL);
    // 2. per-row prep (alpha/beta/gamma transposed to (b,h,l))
    prep_kernel<<<ROWS, 64, 0, stream>>>(zx, dt_bias, A_log, B_norm_w, C_norm_w,
                                         Bg, Cg, aT, bT, gT);
    // 3. cumsum of theta over L
    cumsum_kernel<<<BB * NH, 256, 0, stream>>>(zx, th_cs);
    // 4. rotary on B/C
    rot_kernel<<<(ROWS * 1024) / 256, 256, 0, stream>>>(th_cs, Bg, Cg, B_bias, C_bias,
                                                        Brot, Crot);
    // 5. sequential scan over L (LDS chunk-staged)
    scan_kernel<<<BB * NH * 4, 256, 0, stream>>>(zx, Brot, Crot, aT, bT, gT, Dp, yb);
    // 6. gate + RMS norm
    gate_norm_kernel<<<ROWS, 256, 0, stream>>>(yb, zx, norm_w, gn);
    // 7. out = gn @ out_proj_w^T     (M=2048, N=1024, K=2048)
    gemm_nt<<<dim3(DMODEL / BN, ROWS / BM), 256, 0, stream>>>(
        gn, out_proj_w, out, ROWS, DMODEL, DIN);
}

// Round 6
// 618.126 us; speedup vs baseline: 1.6451x; 1.3196x over previous
//
#include <hip/hip_runtime.h>
#include <hip/hip_bf16.h>

// Problem constants
#define DMODEL 1024
#define DIN    2048
#define NH     32
#define HD     64
#define DS     64
#define LSEQ   1024
#define BB     2
#define DTOT   5312           // 2*DIN + 2*64 + 32 + 1024 + 32
#define ROWS   (BB*LSEQ)      // 2048
// column offsets inside zxbcdt
#define OFF_Z   0
#define OFF_X   2048
#define OFF_BR  4096
#define OFF_CR  4160
#define OFF_DT  4224
#define OFF_TH  4256
#define OFF_LAM 5280
#define NZX     4096          // z+x columns done in bf16 MFMA
#define NREM    (DTOT - NZX)  // 1216 fp32 columns (B,C,dt,theta,lam)

typedef short  s16x8 __attribute__((ext_vector_type(8)));
typedef float  f32x4 __attribute__((ext_vector_type(4)));

__device__ __forceinline__ unsigned int f2bf(float f) {   // RNE f32->bf16 (finite inputs)
    unsigned int u = __float_as_uint(f);
    u += 0x7fffu + ((u >> 16) & 1u);
    return u >> 16;
}

// ---------------------------------------------------------------------------
// bf16 MFMA GEMM for the z/x block: zx[:, 0:4096] = u @ W[0:4096,:]^T
// 128x128 tile, BK=32, 256 threads = 4 waves (2x2), each wave 64x64 out.
// fp32 global loads, inline cvt to bf16, LDS stride 40 halfs (2-way banks max).
// ---------------------------------------------------------------------------
#define LDB 40
__global__ __launch_bounds__(256) void mfma_gemm_zx(const float* __restrict__ u,
                                                    const float* __restrict__ W,
                                                    float* __restrict__ zx) {
    __shared__ unsigned short Al[128][LDB];
    __shared__ unsigned short Bl[128][LDB];
    const int tid = threadIdx.x;
    const int m0 = blockIdx.y * 128, n0 = blockIdx.x * 128;
    const int lane = tid & 63, wave = tid >> 6;
    const int wr = wave >> 1, wc = wave & 1;       // 2x2 waves
    const int lr = lane >> 4, lc = lane & 15;

    const int r  = tid >> 2;                       // staging row 0..63
    const int cb = (tid & 3) * 8;                  // staging col 0,8,16,24

    f32x4 acc[4][4] = {};

    const float* uA = u + (size_t)(m0 + r) * DMODEL + cb;
    const float* uB = W + (size_t)(n0 + r) * DMODEL + cb;

    for (int k0 = 0; k0 < DMODEL; k0 += 32) {
        // global loads (fp32), issued before the barrier
        const float4 a0 = *(const float4*)(uA + k0);
        const float4 a1 = *(const float4*)(uA + k0 + 4);
        const float4 a2 = *(const float4*)(uA + k0 + (size_t)64 * DMODEL);
        const float4 a3 = *(const float4*)(uA + k0 + (size_t)64 * DMODEL + 4);
        const float4 b0 = *(const float4*)(uB + k0);
        const float4 b1 = *(const float4*)(uB + k0 + 4);
        const float4 b2 = *(const float4*)(uB + k0 + (size_t)64 * DMODEL);
        const float4 b3 = *(const float4*)(uB + k0 + (size_t)64 * DMODEL + 4);
        __syncthreads();   // previous iteration's frag reads done
        uint4 q;
        q.x = f2bf(a0.x) | (f2bf(a0.y) << 16); q.y = f2bf(a0.z) | (f2bf(a0.w) << 16);
        q.z = f2bf(a1.x) | (f2bf(a1.y) << 16); q.w = f2bf(a1.z) | (f2bf(a1.w) << 16);
        *(uint4*)&Al[r][cb] = q;
        q.x = f2bf(a2.x) | (f2bf(a2.y) << 16); q.y = f2bf(a2.z) | (f2bf(a2.w) << 16);
        q.z = f2bf(a3.x) | (f2bf(a3.y) << 16); q.w = f2bf(a3.z) | (f2bf(a3.w) << 16);
        *(uint4*)&Al[r + 64][cb] = q;
        q.x = f2bf(b0.x) | (f2bf(b0.y) << 16); q.y = f2bf(b0.z) | (f2bf(b0.w) << 16);
        q.z = f2bf(b1.x) | (f2bf(b1.y) << 16); q.w = f2bf(b1.z) | (f2bf(b1.w) << 16);
        *(uint4*)&Bl[r][cb] = q;
        q.x = f2bf(b2.x) | (f2bf(b2.y) << 16); q.y = f2bf(b2.z) | (f2bf(b2.w) << 16);
        q.z = f2bf(b3.x) | (f2bf(b3.y) << 16); q.w = f2bf(b3.z) | (f2bf(b3.w) << 16);
        *(uint4*)&Bl[r + 64][cb] = q;
        __syncthreads();
        // fragments: lane holds 8 k-contiguous bf16; k-group = lr (k-perm cancels A vs B)
        s16x8 af[4], bf[4];
        #pragma unroll
        for (int f = 0; f < 4; ++f) {
            af[f] = *(const s16x8*)&Al[wr * 64 + f * 16 + lc][lr * 8];
            bf[f] = *(const s16x8*)&Bl[wc * 64 + f * 16 + lc][lr * 8];
        }
        #pragma unroll
        for (int fm = 0; fm < 4; ++fm)
            #pragma unroll
            for (int fn = 0; fn < 4; ++fn)
                acc[fm][fn] = __builtin_amdgcn_mfma_f32_16x16x32_bf16(
                    af[fm], bf[fn], acc[fm][fn], 0, 0, 0);
    }

    // C/D layout (m89-verified): col = lane&15, row = (lane>>4)*4 + j
    #pragma unroll
    for (int fm = 0; fm < 4; ++fm)
        #pragma unroll
        for (int fn = 0; fn < 4; ++fn) {
            const size_t col = n0 + wc * 64 + fn * 16 + lc;
            #pragma unroll
            for (int j = 0; j < 4; ++j) {
                const size_t row = m0 + wr * 64 + fm * 16 + lr * 4 + j;
                zx[row * DTOT + col] = acc[fm][fn][j];
            }
        }
}

// ---------------------------------------------------------------------------
// fp32 GEMM: C[M][N](ldc) = A[M][K] * B[N][K]^T — for the sensitive 1216
// columns (theta cumsum amplifies bf16 error) and for out_proj.
// ---------------------------------------------------------------------------
#define BM 128
#define BN 128
#define BK 16
#define LDT 132

__global__ __launch_bounds__(256) void gemm_nt(const float* __restrict__ A,
                                               const float* __restrict__ B,
                                               float* __restrict__ C,
                                               int M, int N, int K, int ldc) {
    __shared__ float As[BK][LDT];
    __shared__ float Bs[BK][LDT];
    const int tid = threadIdx.x;
    const int tx = tid & 15, ty = tid >> 4;
    const int m0 = blockIdx.y * BM, n0 = blockIdx.x * BN;

    float acc[8][8] = {};

    const int r0 = tid >> 2;
    const int r1 = r0 + 64;
    const int kq = (tid & 3) << 2;

    for (int k0 = 0; k0 < K; k0 += BK) {
        const float4 va0 = *(const float4*)(A + (size_t)(m0 + r0) * K + k0 + kq);
        const float4 va1 = *(const float4*)(A + (size_t)(m0 + r1) * K + k0 + kq);
        const int nb0 = n0 + r0, nb1 = n0 + r1;
        const float4 vb0 = (nb0 < N) ? *(const float4*)(B + (size_t)nb0 * K + k0 + kq)
                                     : make_float4(0.f, 0.f, 0.f, 0.f);
        const float4 vb1 = (nb1 < N) ? *(const float4*)(B + (size_t)nb1 * K + k0 + kq)
                                     : make_float4(0.f, 0.f, 0.f, 0.f);
        __syncthreads();
        As[kq + 0][r0] = va0.x; As[kq + 1][r0] = va0.y; As[kq + 2][r0] = va0.z; As[kq + 3][r0] = va0.w;
        As[kq + 0][r1] = va1.x; As[kq + 1][r1] = va1.y; As[kq + 2][r1] = va1.z; As[kq + 3][r1] = va1.w;
        Bs[kq + 0][r0] = vb0.x; Bs[kq + 1][r0] = vb0.y; Bs[kq + 2][r0] = vb0.z; Bs[kq + 3][r0] = vb0.w;
        Bs[kq + 0][r1] = vb1.x; Bs[kq + 1][r1] = vb1.y; Bs[kq + 2][r1] = vb1.z; Bs[kq + 3][r1] = vb1.w;
        __syncthreads();
        #pragma unroll
        for (int k = 0; k < BK; ++k) {
            const float4 a0 = *(const float4*)&As[k][ty * 4];
            const float4 a1 = *(const float4*)&As[k][64 + ty * 4];
            const float4 b0 = *(const float4*)&Bs[k][tx * 4];
            const float4 b1 = *(const float4*)&Bs[k][64 + tx * 4];
            const float av[8] = {a0.x, a0.y, a0.z, a0.w, a1.x, a1.y, a1.z, a1.w};
            const float bv[8] = {b0.x, b0.y, b0.z, b0.w, b1.x, b1.y, b1.z, b1.w};
            #pragma unroll
            for (int i = 0; i < 8; ++i)
                #pragma unroll
                for (int j = 0; j < 8; ++j)
                    acc[i][j] = fmaf(av[i], bv[j], acc[i][j]);
        }
        __syncthreads();
    }

    #pragma unroll
    for (int i = 0; i < 8; ++i) {
        const int m = m0 + ((i < 4) ? (ty * 4 + i) : (64 + ty * 4 + (i - 4)));
        const int n1 = n0 + tx * 4;
        const int n2 = n0 + 64 + tx * 4;
        if (n1 < N)
            *(float4*)(C + (size_t)m * ldc + n1) = make_float4(acc[i][0], acc[i][1], acc[i][2], acc[i][3]);
        if (n2 < N)
            *(float4*)(C + (size_t)m * ldc + n2) = make_float4(acc[i][4], acc[i][5], acc[i][6], acc[i][7]);
    }
}

// ---------------------------------------------------------------------------
// prep: RMS-norm Br/Cr; alpha/beta/gamma packed as float4 in (b,h,l) layout.
// ---------------------------------------------------------------------------
__global__ __launch_bounds__(64) void prep_kernel(const float* __restrict__ zx,
        const float* __restrict__ dt_bias, const float* __restrict__ A_log,
        const float* __restrict__ B_norm_w, const float* __restrict__ C_norm_w,
        float* __restrict__ Bg, float* __restrict__ Cg,
        float4* __restrict__ abg4) {
    const int bl = blockIdx.x;
    const int b = bl >> 10, l = bl & (LSEQ - 1);
    const int t  = threadIdx.x;
    const float* row = zx + (size_t)bl * DTOT;
    const float br = row[OFF_BR + t];
    const float cr = row[OFF_CR + t];
    float ssb = br * br, ssc = cr * cr;
    #pragma unroll
    for (int k = 1; k < 64; k <<= 1) { ssb += __shfl_xor(ssb, k); ssc += __shfl_xor(ssc, k); }
    const float scB = rsqrtf(ssb * (1.f / 64.f) + 1e-5f);
    const float scC = rsqrtf(ssc * (1.f / 64.f) + 1e-5f);
    Bg[(size_t)bl * 64 + t] = br * scB * B_norm_w[t];
    Cg[(size_t)bl * 64 + t] = cr * scC * C_norm_w[t];
    if (t < NH) {
        const float dtr = row[OFF_DT + t] + dt_bias[t];
        const float dt  = (dtr > 20.f) ? dtr : log1pf(expf(dtr));
        const float lamr = row[OFF_LAM + t];
        const float lam  = 1.f / (1.f + expf(-lamr));
        const float Ah   = -expf(A_log[t]);
        const float al   = expf(dt * Ah);
        const size_t o = ((size_t)b * NH + t) * LSEQ + l;
        abg4[o] = make_float4(al, (1.f - lam) * dt * al, lam * dt, 0.f);
    }
}

// ---------------------------------------------------------------------------
// cumsum of thr over L, per (b,h): 32 dims.
// ---------------------------------------------------------------------------
__global__ __launch_bounds__(256) void cumsum_kernel(const float* __restrict__ zx,
                                                     float* __restrict__ th_cs) {
    const int bh = blockIdx.x;
    const int b = bh >> 5, h = bh & 31;
    const int d = threadIdx.x & 31, seg = threadIdx.x >> 5;
    const float* base = zx + (size_t)b * LSEQ * DTOT + OFF_TH + h * 32 + d;
    float* out = th_cs + (size_t)b * LSEQ * 1024 + h * 32 + d;
    __shared__ float sums[8][33];
    const int l0 = seg * 128;
    float s = 0.f;
    #pragma unroll 4
    for (int i = 0; i < 128; ++i) s += base[(size_t)(l0 + i) * DTOT];
    sums[seg][d] = s;
    __syncthreads();
    float acc = 0.f;
    for (int s2 = 0; s2 < seg; ++s2) acc += sums[s2][d];
    #pragma unroll 4
    for (int i = 0; i < 128; ++i) {
        acc += base[(size_t)(l0 + i) * DTOT];
        out[(size_t)(l0 + i) * 1024] = acc;
    }
}

// ---------------------------------------------------------------------------
// rot: Bh/Ch = rot(broadcast(Bg/Cg)+bias). Brot/Crot layout (B,NH,L,DS).
// ---------------------------------------------------------------------------
__global__ __launch_bounds__(256) void rot_kernel(const float* __restrict__ th_cs,
        const float* __restrict__ Bg, const float* __restrict__ Cg,
        const float* __restrict__ B_bias, const float* __restrict__ C_bias,
        float* __restrict__ Brot, float* __restrict__ Crot) {
    const size_t idx = (size_t)blockIdx.x * 256 + threadIdx.x;
    const int j = (int)(idx & 31);
    const int h = (int)((idx >> 5) & 31);
    const size_t bl = idx >> 10;
    const int l = (int)(bl & (LSEQ - 1));
    const int b = (int)(bl >> 10);
    const float th = th_cs[idx];
    float s, c;
    sincosf(th, &s, &c);
    float v1 = Bg[bl * 64 + j]      + B_bias[h * 64 + j];
    float v2 = Bg[bl * 64 + 32 + j] + B_bias[h * 64 + 32 + j];
    const size_t ob = ((size_t)(b * NH + h) * LSEQ + l) * DS + j;
    Brot[ob]      = v1 * c - v2 * s;
    Brot[ob + 32] = v1 * s + v2 * c;
    v1 = Cg[bl * 64 + j]      + C_bias[h * 64 + j];
    v2 = Cg[bl * 64 + 32 + j] + C_bias[h * 64 + 32 + j];
    Crot[ob]      = v1 * c - v2 * s;
    Crot[ob + 32] = v1 * s + v2 * c;
}

// ---------------------------------------------------------------------------
// DPP 16-lane row sum (VALU pipe, replaces 4 ds_swizzle shuffles).
// After the 4 stages, lane 15 of each 16-lane row holds the full row sum.
// ---------------------------------------------------------------------------
__device__ __forceinline__ float row_sum16(float x) {
    int t;
    t = __builtin_amdgcn_update_dpp(0, __float_as_int(x), 0x111, 0xf, 0xf, true); // row_shr:1
    x += __int_as_float(t);
    t = __builtin_amdgcn_update_dpp(0, __float_as_int(x), 0x112, 0xf, 0xf, true); // row_shr:2
    x += __int_as_float(t);
    t = __builtin_amdgcn_update_dpp(0, __float_as_int(x), 0x114, 0xf, 0xf, true); // row_shr:4
    x += __int_as_float(t);
    t = __builtin_amdgcn_update_dpp(0, __float_as_int(x), 0x118, 0xf, 0xf, true); // row_shr:8
    x += __int_as_float(t);
    return x;
}

// ---------------------------------------------------------------------------
// scan: LDS chunk-staged (CH=32), double-buffered; per-step LDS ops cut to 4
// (B b128, C b128, abg b128, x b32) + DPP reduction on the VALU pipe.
// ---------------------------------------------------------------------------
#define CH 32
#define NC (LSEQ / CH)

__global__ __launch_bounds__(256) void scan_kernel(const float* __restrict__ zx,
        const float* __restrict__ Brot, const float* __restrict__ Crot,
        const float4* __restrict__ abg4, const float* __restrict__ Dp,
        float* __restrict__ yb) {
    const int blk = blockIdx.x;
    const int ptile = blk & 3, h = (blk >> 2) & 31, b = blk >> 7;
    const int tid = threadIdx.x;
    const int pl = tid >> 4, ng = tid & 15;
    const int p = ptile * 16 + pl;
    const int n0 = ng * 4;

    __shared__ float  Bsh[2][CH][DS];
    __shared__ float  Csh[2][CH][DS];
    __shared__ float  xsh[2][CH][16];
    __shared__ float4 absh[2][CH];

    const size_t bh = (size_t)b * NH + h;
    const float* Bbase = Brot + bh * LSEQ * DS;
    const float* Cbase = Crot + bh * LSEQ * DS;
    const float4* abase = abg4 + bh * LSEQ;
    const float* xbase = zx + (size_t)b * LSEQ * DTOT + OFF_X + h * HD + ptile * 16;
    const float Dh = Dp[h];
    float* ybase = yb + (size_t)b * LSEQ * DIN + h * HD + p;

    float4 rb0, rb1, rc0, rc1, rx, rab;
    const int xs_s = tid >> 2, xs_q = (tid & 3) * 4;

#define STAGE_LOAD(chv) {                                                           \
        const int c0 = (chv) * CH;                                                  \
        rb0 = *(const float4*)(Bbase + (size_t)c0 * DS + tid * 8);                  \
        rb1 = *(const float4*)(Bbase + (size_t)c0 * DS + tid * 8 + 4);              \
        rc0 = *(const float4*)(Cbase + (size_t)c0 * DS + tid * 8);                  \
        rc1 = *(const float4*)(Cbase + (size_t)c0 * DS + tid * 8 + 4);              \
        if (tid < 128)                                                              \
            rx = *(const float4*)(xbase + (size_t)(c0 + xs_s) * DTOT + xs_q);       \
        if (tid < CH) rab = abase[c0 + tid];                                        \
    }

#define STAGE_WRITE(cur) {                                                          \
        float* bfp = &Bsh[cur][0][0]; float* cfp = &Csh[cur][0][0];                 \
        *(float4*)(bfp + tid * 8)     = rb0;  *(float4*)(bfp + tid * 8 + 4) = rb1;  \
        *(float4*)(cfp + tid * 8)     = rc0;  *(float4*)(cfp + tid * 8 + 4) = rc1;  \
        if (tid < 128) *(float4*)(&xsh[cur][0][0] + tid * 4) = rx;                  \
        if (tid < CH) absh[cur][tid] = rab;                                         \
    }

    float hs0 = 0.f, hs1 = 0.f, hs2 = 0.f, hs3 = 0.f;
    float Bp0 = 0.f, Bp1 = 0.f, Bp2 = 0.f, Bp3 = 0.f;
    float xprev = 0.f;

    STAGE_LOAD(0);
    int cur = 0;
    for (int ch = 0; ch < NC; ++ch) {
        STAGE_WRITE(cur);
        __syncthreads();
        if (ch + 1 < NC) STAGE_LOAD(ch + 1);
        const int t0 = ch * CH;
        #pragma unroll 4
        for (int s = 0; s < CH; ++s) {
            const float4 Bv = *(const float4*)&Bsh[cur][s][n0];
            const float4 Cv = *(const float4*)&Csh[cur][s][n0];
            const float xv = xsh[cur][s][pl];
            const float4 ab = absh[cur][s];
            const float cp = ab.y * xprev;
            const float cc = ab.z * xv;
            float ys;
            hs0 = fmaf(ab.x, hs0, fmaf(cp, Bp0, cc * Bv.x)); ys  = Cv.x * hs0;
            hs1 = fmaf(ab.x, hs1, fmaf(cp, Bp1, cc * Bv.y)); ys += Cv.y * hs1;
            hs2 = fmaf(ab.x, hs2, fmaf(cp, Bp2, cc * Bv.z)); ys += Cv.z * hs2;
            hs3 = fmaf(ab.x, hs3, fmaf(cp, Bp3, cc * Bv.w)); ys += Cv.w * hs3;
            ys = row_sum16(ys);
            if (ng == 15) ybase[(size_t)(t0 + s) * DIN] = fmaf(Dh, xv, ys);
            Bp0 = Bv.x; Bp1 = Bv.y; Bp2 = Bv.z; Bp3 = Bv.w;
            xprev = xv;
        }
        cur ^= 1;
    }
#undef STAGE_LOAD
#undef STAGE_WRITE
}

// ---------------------------------------------------------------------------
// gate + final RMS norm
// ---------------------------------------------------------------------------
__global__ __launch_bounds__(256) void gate_norm_kernel(const float* __restrict__ yb,
        const float* __restrict__ zx, const float* __restrict__ norm_w,
        float* __restrict__ gn) {
    const int bl = blockIdx.x;
    const int tid = threadIdx.x;
    const float* yrow = yb + (size_t)bl * DIN;
    const float* zrow = zx + (size_t)bl * DTOT + OFF_Z;
    float g[8];
    float ss = 0.f;
    #pragma unroll
    for (int i = 0; i < 8; ++i) {
        const int c = tid + i * 256;
        const float yv = yrow[c];
        const float zv = zrow[c];
        const float sg = 1.f / (1.f + expf(-zv));
        const float gv = yv * zv * sg;
        g[i] = gv;
        ss += gv * gv;
    }
    #pragma unroll
    for (int k = 1; k < 64; k <<= 1) ss += __shfl_xor(ss, k);
    __shared__ float wsum[4];
    if ((tid & 63) == 0) wsum[tid >> 6] = ss;
    __syncthreads();
    ss = wsum[0] + wsum[1] + wsum[2] + wsum[3];
    const float sc = rsqrtf(ss * (1.f / 2048.f) + 1e-5f);
    #pragma unroll
    for (int i = 0; i < 8; ++i) {
        const int c = tid + i * 256;
        gn[(size_t)bl * DIN + c] = g[i] * sc * norm_w[c];
    }
}

// ---------------------------------------------------------------------------
extern "C" void kernel_launch(void* const* d_in, const int* in_sizes, int n_in,
                              void* d_out, int out_size, void* d_ws, size_t ws_size,
                              hipStream_t stream) {
    const float* u          = (const float*)d_in[0];
    const float* in_proj_w  = (const float*)d_in[1];
    const float* dt_bias    = (const float*)d_in[2];
    const float* A_log      = (const float*)d_in[3];
    const float* Dp         = (const float*)d_in[4];
    const float* B_norm_w   = (const float*)d_in[5];
    const float* C_norm_w   = (const float*)d_in[6];
    const float* B_bias     = (const float*)d_in[7];
    const float* C_bias     = (const float*)d_in[8];
    const float* norm_w     = (const float*)d_in[9];
    const float* out_proj_w = (const float*)d_in[10];
    float* out = (float*)d_out;

    float* p = (float*)d_ws;
    float* zx    = p; p += (size_t)ROWS * DTOT;
    float* th_cs = p; p += (size_t)ROWS * 1024;
    float* Brot  = p; p += (size_t)ROWS * 2048;
    float* Crot  = p; p += (size_t)ROWS * 2048;
    float* Bg    = p; p += (size_t)ROWS * 64;
    float* Cg    = p; p += (size_t)ROWS * 64;
    float4* abg4 = (float4*)p; p += (size_t)ROWS * NH * 4;
    float* yb    = p; p += (size_t)ROWS * 2048;
    float* gn    = Brot;   // reuse: Brot dead after scan

    // 1a. z/x block via bf16 MFMA: zx[:, 0:4096]
    mfma_gemm_zx<<<dim3(NZX / 128, ROWS / 128), 256, 0, stream>>>(u, in_proj_w, zx);
    // 1b. sensitive columns in fp32: zx[:, 4096:5312]
    gemm_nt<<<dim3((NREM + BN - 1) / BN, ROWS / BM), 256, 0, stream>>>(
        u, in_proj_w + (size_t)NZX * DMODEL, zx + NZX, ROWS, NREM, DMODEL, DTOT);
    // 2. per-row prep
    prep_kernel<<<ROWS, 64, 0, stream>>>(zx, dt_bias, A_log, B_norm_w, C_norm_w,
                                         Bg, Cg, abg4);
    // 3. cumsum of theta over L
    cumsum_kernel<<<BB * NH, 256, 0, stream>>>(zx, th_cs);
    // 4. rotary on B/C
    rot_kernel<<<(ROWS * 1024) / 256, 256, 0, stream>>>(th_cs, Bg, Cg, B_bias, C_bias,
                                                        Brot, Crot);
    // 5. sequential scan over L
    scan_kernel<<<BB * NH * 4, 256, 0, stream>>>(zx, Brot, Crot, abg4, Dp, yb);
    // 6. gate + RMS norm
    gate_norm_kernel<<<ROWS, 256, 0, stream>>>(yb, zx, norm_w, gn);
    // 7. out = gn @ out_proj_w^T
    gemm_nt<<<dim3(DMODEL / BN, ROWS / BM), 256, 0, stream>>>(
        gn, out_proj_w, out, ROWS, DMODEL, DIN, DMODEL);
}

// Round 7
// 323.123 us; speedup vs baseline: 3.1470x; 1.9130x over previous
//
#include <hip/hip_runtime.h>
#include <hip/hip_bf16.h>

// Problem constants
#define DMODEL 1024
#define DIN    2048
#define NH     32
#define HD     64
#define DS     64
#define LSEQ   1024
#define BB     2
#define DTOT   5312           // 2*DIN + 2*64 + 32 + 1024 + 32
#define ROWS   (BB*LSEQ)      // 2048
// column offsets inside zxbcdt
#define OFF_Z   0
#define OFF_X   2048
#define OFF_BR  4096
#define OFF_CR  4160
#define OFF_DT  4224
#define OFF_TH  4256
#define OFF_LAM 5280
#define NZX     4096          // z+x columns done in single-pass bf16 MFMA
#define NREM    (DTOT - NZX)  // 1216 cols done in 3-pass split-bf16 MFMA

typedef short  s16x8 __attribute__((ext_vector_type(8)));
typedef float  f32x4 __attribute__((ext_vector_type(4)));

__device__ __forceinline__ unsigned int f2bf(float f) {   // RNE f32->bf16 (finite inputs)
    unsigned int u = __float_as_uint(f);
    u += 0x7fffu + ((u >> 16) & 1u);
    return u >> 16;
}
// pack two floats to bf16x2
__device__ __forceinline__ unsigned int pk(float x, float y) {
    return f2bf(x) | (f2bf(y) << 16);
}
// split two floats into bf16x2 hi + bf16x2 lo (residual)
__device__ __forceinline__ void split2(float x, float y, unsigned int& h, unsigned int& l) {
    const unsigned int hx = f2bf(x), hy = f2bf(y);
    h = hx | (hy << 16);
    l = pk(x - __uint_as_float(hx << 16), y - __uint_as_float(hy << 16));
}

// ---------------------------------------------------------------------------
// bf16 MFMA GEMM, z/x block: zx[:, 0:4096] = u @ W[0:4096,:]^T
// 128x128 tile, BK=32, 4 waves (2x2), wave = 64x64 out.
// ---------------------------------------------------------------------------
#define LDB 40
__global__ __launch_bounds__(256) void mfma_gemm_zx(const float* __restrict__ u,
                                                    const float* __restrict__ W,
                                                    float* __restrict__ zx) {
    __shared__ unsigned short Al[128][LDB];
    __shared__ unsigned short Bl[128][LDB];
    const int tid = threadIdx.x;
    const int m0 = blockIdx.y * 128, n0 = blockIdx.x * 128;
    const int lane = tid & 63, wave = tid >> 6;
    const int wr = wave >> 1, wc = wave & 1;
    const int lr = lane >> 4, lc = lane & 15;
    const int r  = tid >> 2;
    const int cb = (tid & 3) * 8;

    f32x4 acc[4][4] = {};

    const float* uA = u + (size_t)(m0 + r) * DMODEL + cb;
    const float* uB = W + (size_t)(n0 + r) * DMODEL + cb;

    for (int k0 = 0; k0 < DMODEL; k0 += 32) {
        const float4 a0 = *(const float4*)(uA + k0);
        const float4 a1 = *(const float4*)(uA + k0 + 4);
        const float4 a2 = *(const float4*)(uA + k0 + (size_t)64 * DMODEL);
        const float4 a3 = *(const float4*)(uA + k0 + (size_t)64 * DMODEL + 4);
        const float4 b0 = *(const float4*)(uB + k0);
        const float4 b1 = *(const float4*)(uB + k0 + 4);
        const float4 b2 = *(const float4*)(uB + k0 + (size_t)64 * DMODEL);
        const float4 b3 = *(const float4*)(uB + k0 + (size_t)64 * DMODEL + 4);
        __syncthreads();
        uint4 q;
        q.x = pk(a0.x, a0.y); q.y = pk(a0.z, a0.w); q.z = pk(a1.x, a1.y); q.w = pk(a1.z, a1.w);
        *(uint4*)&Al[r][cb] = q;
        q.x = pk(a2.x, a2.y); q.y = pk(a2.z, a2.w); q.z = pk(a3.x, a3.y); q.w = pk(a3.z, a3.w);
        *(uint4*)&Al[r + 64][cb] = q;
        q.x = pk(b0.x, b0.y); q.y = pk(b0.z, b0.w); q.z = pk(b1.x, b1.y); q.w = pk(b1.z, b1.w);
        *(uint4*)&Bl[r][cb] = q;
        q.x = pk(b2.x, b2.y); q.y = pk(b2.z, b2.w); q.z = pk(b3.x, b3.y); q.w = pk(b3.z, b3.w);
        *(uint4*)&Bl[r + 64][cb] = q;
        __syncthreads();
        s16x8 af[4], bf[4];
        #pragma unroll
        for (int f = 0; f < 4; ++f) {
            af[f] = *(const s16x8*)&Al[wr * 64 + f * 16 + lc][lr * 8];
            bf[f] = *(const s16x8*)&Bl[wc * 64 + f * 16 + lc][lr * 8];
        }
        #pragma unroll
        for (int fm = 0; fm < 4; ++fm)
            #pragma unroll
            for (int fn = 0; fn < 4; ++fn)
                acc[fm][fn] = __builtin_amdgcn_mfma_f32_16x16x32_bf16(
                    af[fm], bf[fn], acc[fm][fn], 0, 0, 0);
    }

    #pragma unroll
    for (int fm = 0; fm < 4; ++fm)
        #pragma unroll
        for (int fn = 0; fn < 4; ++fn) {
            const size_t col = n0 + wc * 64 + fn * 16 + lc;
            #pragma unroll
            for (int j = 0; j < 4; ++j) {
                const size_t row = m0 + wr * 64 + fm * 16 + lr * 4 + j;
                zx[row * DTOT + col] = acc[fm][fn][j];
            }
        }
}

// ---------------------------------------------------------------------------
// bf16 MFMA GEMM, generic 128x64 tile single-pass: C = A[M][K] @ B[N][K]^T
// 4 waves (2x2), wave = 64x32 out. Used for out_proj (N=1024, K=2048).
// ---------------------------------------------------------------------------
__global__ __launch_bounds__(256) void mfma_gemm_out(const float* __restrict__ A,
                                                     const float* __restrict__ B,
                                                     float* __restrict__ C,
                                                     int K, int ldc) {
    __shared__ unsigned short Als[128][LDB];
    __shared__ unsigned short Bls[64][LDB];
    const int tid = threadIdx.x;
    const int m0 = blockIdx.y * 128, n0 = blockIdx.x * 64;
    const int lane = tid & 63, wave = tid >> 6;
    const int wr = wave >> 1, wc = wave & 1;
    const int lr = lane >> 4, lc = lane & 15;
    const int r  = tid >> 2;
    const int cb = (tid & 3) * 8;

    f32x4 acc[4][2] = {};

    const float* pA = A + (size_t)(m0 + r) * K + cb;
    const float* pB = B + (size_t)(n0 + r) * K + cb;

    for (int k0 = 0; k0 < K; k0 += 32) {
        const float4 a0 = *(const float4*)(pA + k0);
        const float4 a1 = *(const float4*)(pA + k0 + 4);
        const float4 a2 = *(const float4*)(pA + k0 + (size_t)64 * K);
        const float4 a3 = *(const float4*)(pA + k0 + (size_t)64 * K + 4);
        const float4 b0 = *(const float4*)(pB + k0);
        const float4 b1 = *(const float4*)(pB + k0 + 4);
        __syncthreads();
        uint4 q;
        q.x = pk(a0.x, a0.y); q.y = pk(a0.z, a0.w); q.z = pk(a1.x, a1.y); q.w = pk(a1.z, a1.w);
        *(uint4*)&Als[r][cb] = q;
        q.x = pk(a2.x, a2.y); q.y = pk(a2.z, a2.w); q.z = pk(a3.x, a3.y); q.w = pk(a3.z, a3.w);
        *(uint4*)&Als[r + 64][cb] = q;
        q.x = pk(b0.x, b0.y); q.y = pk(b0.z, b0.w); q.z = pk(b1.x, b1.y); q.w = pk(b1.z, b1.w);
        *(uint4*)&Bls[r][cb] = q;
        __syncthreads();
        s16x8 af[4], bf[2];
        #pragma unroll
        for (int f = 0; f < 4; ++f)
            af[f] = *(const s16x8*)&Als[wr * 64 + f * 16 + lc][lr * 8];
        #pragma unroll
        for (int f = 0; f < 2; ++f)
            bf[f] = *(const s16x8*)&Bls[wc * 32 + f * 16 + lc][lr * 8];
        #pragma unroll
        for (int fm = 0; fm < 4; ++fm)
            #pragma unroll
            for (int fn = 0; fn < 2; ++fn)
                acc[fm][fn] = __builtin_amdgcn_mfma_f32_16x16x32_bf16(
                    af[fm], bf[fn], acc[fm][fn], 0, 0, 0);
    }

    #pragma unroll
    for (int fm = 0; fm < 4; ++fm)
        #pragma unroll
        for (int fn = 0; fn < 2; ++fn) {
            const size_t col = n0 + wc * 32 + fn * 16 + lc;
            #pragma unroll
            for (int j = 0; j < 4; ++j) {
                const size_t row = m0 + wr * 64 + fm * 16 + lr * 4 + j;
                C[row * (size_t)ldc + col] = acc[fm][fn][j];
            }
        }
}

// ---------------------------------------------------------------------------
// split-bf16 3-pass MFMA GEMM for the sensitive columns (theta cumsum!):
// u=uh+ul, W=wh+wl; acc += uh*wh + uh*wl + ul*wh  (~fp32 accuracy, MFMA speed)
// 128x64 tile, N=1216=19*64 exact. ldc=DTOT, out offset +NZX by caller.
// ---------------------------------------------------------------------------
__global__ __launch_bounds__(256) void mfma_gemm_rem3(const float* __restrict__ u,
                                                      const float* __restrict__ W,
                                                      float* __restrict__ zxr) {
    __shared__ unsigned short Ah[128][LDB], Alo[128][LDB];
    __shared__ unsigned short Bh[64][LDB],  Blo[64][LDB];
    const int tid = threadIdx.x;
    const int m0 = blockIdx.y * 128, n0 = blockIdx.x * 64;
    const int lane = tid & 63, wave = tid >> 6;
    const int wr = wave >> 1, wc = wave & 1;
    const int lr = lane >> 4, lc = lane & 15;
    const int r  = tid >> 2;
    const int cb = (tid & 3) * 8;

    f32x4 acc[4][2] = {};

    const float* pA = u + (size_t)(m0 + r) * DMODEL + cb;
    const float* pB = W + (size_t)(n0 + r) * DMODEL + cb;   // n0+r <= 1215 < NREM

    for (int k0 = 0; k0 < DMODEL; k0 += 32) {
        const float4 a0 = *(const float4*)(pA + k0);
        const float4 a1 = *(const float4*)(pA + k0 + 4);
        const float4 a2 = *(const float4*)(pA + k0 + (size_t)64 * DMODEL);
        const float4 a3 = *(const float4*)(pA + k0 + (size_t)64 * DMODEL + 4);
        const float4 b0 = *(const float4*)(pB + k0);
        const float4 b1 = *(const float4*)(pB + k0 + 4);
        __syncthreads();
        uint4 qh, ql;
        split2(a0.x, a0.y, qh.x, ql.x); split2(a0.z, a0.w, qh.y, ql.y);
        split2(a1.x, a1.y, qh.z, ql.z); split2(a1.z, a1.w, qh.w, ql.w);
        *(uint4*)&Ah[r][cb] = qh; *(uint4*)&Alo[r][cb] = ql;
        split2(a2.x, a2.y, qh.x, ql.x); split2(a2.z, a2.w, qh.y, ql.y);
        split2(a3.x, a3.y, qh.z, ql.z); split2(a3.z, a3.w, qh.w, ql.w);
        *(uint4*)&Ah[r + 64][cb] = qh; *(uint4*)&Alo[r + 64][cb] = ql;
        split2(b0.x, b0.y, qh.x, ql.x); split2(b0.z, b0.w, qh.y, ql.y);
        split2(b1.x, b1.y, qh.z, ql.z); split2(b1.z, b1.w, qh.w, ql.w);
        *(uint4*)&Bh[r][cb] = qh; *(uint4*)&Blo[r][cb] = ql;
        __syncthreads();
        s16x8 ahf[4], alf[4], bhf[2], blf[2];
        #pragma unroll
        for (int f = 0; f < 4; ++f) {
            ahf[f] = *(const s16x8*)&Ah[wr * 64 + f * 16 + lc][lr * 8];
            alf[f] = *(const s16x8*)&Alo[wr * 64 + f * 16 + lc][lr * 8];
        }
        #pragma unroll
        for (int f = 0; f < 2; ++f) {
            bhf[f] = *(const s16x8*)&Bh[wc * 32 + f * 16 + lc][lr * 8];
            blf[f] = *(const s16x8*)&Blo[wc * 32 + f * 16 + lc][lr * 8];
        }
        #pragma unroll
        for (int fm = 0; fm < 4; ++fm)
            #pragma unroll
            for (int fn = 0; fn < 2; ++fn) {
                acc[fm][fn] = __builtin_amdgcn_mfma_f32_16x16x32_bf16(
                    ahf[fm], bhf[fn], acc[fm][fn], 0, 0, 0);
                acc[fm][fn] = __builtin_amdgcn_mfma_f32_16x16x32_bf16(
                    ahf[fm], blf[fn], acc[fm][fn], 0, 0, 0);
                acc[fm][fn] = __builtin_amdgcn_mfma_f32_16x16x32_bf16(
                    alf[fm], bhf[fn], acc[fm][fn], 0, 0, 0);
            }
    }

    #pragma unroll
    for (int fm = 0; fm < 4; ++fm)
        #pragma unroll
        for (int fn = 0; fn < 2; ++fn) {
            const size_t col = n0 + wc * 32 + fn * 16 + lc;
            #pragma unroll
            for (int j = 0; j < 4; ++j) {
                const size_t row = m0 + wr * 64 + fm * 16 + lr * 4 + j;
                zxr[row * DTOT + col] = acc[fm][fn][j];
            }
        }
}

// ---------------------------------------------------------------------------
// prep: RMS-norm Br/Cr; alpha/beta/gamma packed as float4 in (b,h,l) layout.
// ---------------------------------------------------------------------------
__global__ __launch_bounds__(64) void prep_kernel(const float* __restrict__ zx,
        const float* __restrict__ dt_bias, const float* __restrict__ A_log,
        const float* __restrict__ B_norm_w, const float* __restrict__ C_norm_w,
        float* __restrict__ Bg, float* __restrict__ Cg,
        float4* __restrict__ abg4) {
    const int bl = blockIdx.x;
    const int b = bl >> 10, l = bl & (LSEQ - 1);
    const int t  = threadIdx.x;
    const float* row = zx + (size_t)bl * DTOT;
    const float br = row[OFF_BR + t];
    const float cr = row[OFF_CR + t];
    float ssb = br * br, ssc = cr * cr;
    #pragma unroll
    for (int k = 1; k < 64; k <<= 1) { ssb += __shfl_xor(ssb, k); ssc += __shfl_xor(ssc, k); }
    const float scB = rsqrtf(ssb * (1.f / 64.f) + 1e-5f);
    const float scC = rsqrtf(ssc * (1.f / 64.f) + 1e-5f);
    Bg[(size_t)bl * 64 + t] = br * scB * B_norm_w[t];
    Cg[(size_t)bl * 64 + t] = cr * scC * C_norm_w[t];
    if (t < NH) {
        const float dtr = row[OFF_DT + t] + dt_bias[t];
        const float dt  = (dtr > 20.f) ? dtr : log1pf(expf(dtr));
        const float lamr = row[OFF_LAM + t];
        const float lam  = 1.f / (1.f + expf(-lamr));
        const float Ah   = -expf(A_log[t]);
        const float al   = expf(dt * Ah);
        const size_t o = ((size_t)b * NH + t) * LSEQ + l;
        abg4[o] = make_float4(al, (1.f - lam) * dt * al, lam * dt, 0.f);
    }
}

// ---------------------------------------------------------------------------
// cumsum of thr over L, per (b,h): 32 dims.
// ---------------------------------------------------------------------------
__global__ __launch_bounds__(256) void cumsum_kernel(const float* __restrict__ zx,
                                                     float* __restrict__ th_cs) {
    const int bh = blockIdx.x;
    const int b = bh >> 5, h = bh & 31;
    const int d = threadIdx.x & 31, seg = threadIdx.x >> 5;
    const float* base = zx + (size_t)b * LSEQ * DTOT + OFF_TH + h * 32 + d;
    float* out = th_cs + (size_t)b * LSEQ * 1024 + h * 32 + d;
    __shared__ float sums[8][33];
    const int l0 = seg * 128;
    float s = 0.f;
    #pragma unroll 4
    for (int i = 0; i < 128; ++i) s += base[(size_t)(l0 + i) * DTOT];
    sums[seg][d] = s;
    __syncthreads();
    float acc = 0.f;
    for (int s2 = 0; s2 < seg; ++s2) acc += sums[s2][d];
    #pragma unroll 4
    for (int i = 0; i < 128; ++i) {
        acc += base[(size_t)(l0 + i) * DTOT];
        out[(size_t)(l0 + i) * 1024] = acc;
    }
}

// ---------------------------------------------------------------------------
// rot: Bh/Ch = rot(broadcast(Bg/Cg)+bias). Brot/Crot layout (B,NH,L,DS).
// ---------------------------------------------------------------------------
__global__ __launch_bounds__(256) void rot_kernel(const float* __restrict__ th_cs,
        const float* __restrict__ Bg, const float* __restrict__ Cg,
        const float* __restrict__ B_bias, const float* __restrict__ C_bias,
        float* __restrict__ Brot, float* __restrict__ Crot) {
    const size_t idx = (size_t)blockIdx.x * 256 + threadIdx.x;
    const int j = (int)(idx & 31);
    const int h = (int)((idx >> 5) & 31);
    const size_t bl = idx >> 10;
    const int l = (int)(bl & (LSEQ - 1));
    const int b = (int)(bl >> 10);
    const float th = th_cs[idx];
    float s, c;
    sincosf(th, &s, &c);
    float v1 = Bg[bl * 64 + j]      + B_bias[h * 64 + j];
    float v2 = Bg[bl * 64 + 32 + j] + B_bias[h * 64 + 32 + j];
    const size_t ob = ((size_t)(b * NH + h) * LSEQ + l) * DS + j;
    Brot[ob]      = v1 * c - v2 * s;
    Brot[ob + 32] = v1 * s + v2 * c;
    v1 = Cg[bl * 64 + j]      + C_bias[h * 64 + j];
    v2 = Cg[bl * 64 + 32 + j] + C_bias[h * 64 + 32 + j];
    Crot[ob]      = v1 * c - v2 * s;
    Crot[ob + 32] = v1 * s + v2 * c;
}

// ---------------------------------------------------------------------------
// DPP 16-lane row sum (VALU pipe). Lane 15 of each 16-lane row holds the sum.
// ---------------------------------------------------------------------------
__device__ __forceinline__ float row_sum16(float x) {
    int t;
    t = __builtin_amdgcn_update_dpp(0, __float_as_int(x), 0x111, 0xf, 0xf, true);
    x += __int_as_float(t);
    t = __builtin_amdgcn_update_dpp(0, __float_as_int(x), 0x112, 0xf, 0xf, true);
    x += __int_as_float(t);
    t = __builtin_amdgcn_update_dpp(0, __float_as_int(x), 0x114, 0xf, 0xf, true);
    x += __int_as_float(t);
    t = __builtin_amdgcn_update_dpp(0, __float_as_int(x), 0x118, 0xf, 0xf, true);
    x += __int_as_float(t);
    return x;
}

// ---------------------------------------------------------------------------
// scan: LDS chunk-staged (CH=32), double-buffered; 4 LDS ops/step + DPP reduce.
// ---------------------------------------------------------------------------
#define CH 32
#define NC (LSEQ / CH)

__global__ __launch_bounds__(256) void scan_kernel(const float* __restrict__ zx,
        const float* __restrict__ Brot, const float* __restrict__ Crot,
        const float4* __restrict__ abg4, const float* __restrict__ Dp,
        float* __restrict__ yb) {
    const int blk = blockIdx.x;
    const int ptile = blk & 3, h = (blk >> 2) & 31, b = blk >> 7;
    const int tid = threadIdx.x;
    const int pl = tid >> 4, ng = tid & 15;
    const int p = ptile * 16 + pl;
    const int n0 = ng * 4;

    __shared__ float  Bsh[2][CH][DS];
    __shared__ float  Csh[2][CH][DS];
    __shared__ float  xsh[2][CH][16];
    __shared__ float4 absh[2][CH];

    const size_t bh = (size_t)b * NH + h;
    const float* Bbase = Brot + bh * LSEQ * DS;
    const float* Cbase = Crot + bh * LSEQ * DS;
    const float4* abase = abg4 + bh * LSEQ;
    const float* xbase = zx + (size_t)b * LSEQ * DTOT + OFF_X + h * HD + ptile * 16;
    const float Dh = Dp[h];
    float* ybase = yb + (size_t)b * LSEQ * DIN + h * HD + p;

    float4 rb0, rb1, rc0, rc1, rx, rab;
    const int xs_s = tid >> 2, xs_q = (tid & 3) * 4;

#define STAGE_LOAD(chv) {                                                           \
        const int c0 = (chv) * CH;                                                  \
        rb0 = *(const float4*)(Bbase + (size_t)c0 * DS + tid * 8);                  \
        rb1 = *(const float4*)(Bbase + (size_t)c0 * DS + tid * 8 + 4);              \
        rc0 = *(const float4*)(Cbase + (size_t)c0 * DS + tid * 8);                  \
        rc1 = *(const float4*)(Cbase + (size_t)c0 * DS + tid * 8 + 4);              \
        if (tid < 128)                                                              \
            rx = *(const float4*)(xbase + (size_t)(c0 + xs_s) * DTOT + xs_q);       \
        if (tid < CH) rab = abase[c0 + tid];                                        \
    }

#define STAGE_WRITE(cur) {                                                          \
        float* bfp = &Bsh[cur][0][0]; float* cfp = &Csh[cur][0][0];                 \
        *(float4*)(bfp + tid * 8)     = rb0;  *(float4*)(bfp + tid * 8 + 4) = rb1;  \
        *(float4*)(cfp + tid * 8)     = rc0;  *(float4*)(cfp + tid * 8 + 4) = rc1;  \
        if (tid < 128) *(float4*)(&xsh[cur][0][0] + tid * 4) = rx;                  \
        if (tid < CH) absh[cur][tid] = rab;                                         \
    }

    float hs0 = 0.f, hs1 = 0.f, hs2 = 0.f, hs3 = 0.f;
    float Bp0 = 0.f, Bp1 = 0.f, Bp2 = 0.f, Bp3 = 0.f;
    float xprev = 0.f;

    STAGE_LOAD(0);
    int cur = 0;
    for (int ch = 0; ch < NC; ++ch) {
        STAGE_WRITE(cur);
        __syncthreads();
        if (ch + 1 < NC) STAGE_LOAD(ch + 1);
        const int t0 = ch * CH;
        #pragma unroll 4
        for (int s = 0; s < CH; ++s) {
            const float4 Bv = *(const float4*)&Bsh[cur][s][n0];
            const float4 Cv = *(const float4*)&Csh[cur][s][n0];
            const float xv = xsh[cur][s][pl];
            const float4 ab = absh[cur][s];
            const float cp = ab.y * xprev;
            const float cc = ab.z * xv;
            float ys;
            hs0 = fmaf(ab.x, hs0, fmaf(cp, Bp0, cc * Bv.x)); ys  = Cv.x * hs0;
            hs1 = fmaf(ab.x, hs1, fmaf(cp, Bp1, cc * Bv.y)); ys += Cv.y * hs1;
            hs2 = fmaf(ab.x, hs2, fmaf(cp, Bp2, cc * Bv.z)); ys += Cv.z * hs2;
            hs3 = fmaf(ab.x, hs3, fmaf(cp, Bp3, cc * Bv.w)); ys += Cv.w * hs3;
            ys = row_sum16(ys);
            if (ng == 15) ybase[(size_t)(t0 + s) * DIN] = fmaf(Dh, xv, ys);
            Bp0 = Bv.x; Bp1 = Bv.y; Bp2 = Bv.z; Bp3 = Bv.w;
            xprev = xv;
        }
        cur ^= 1;
    }
#undef STAGE_LOAD
#undef STAGE_WRITE
}

// ---------------------------------------------------------------------------
// gate + final RMS norm
// ---------------------------------------------------------------------------
__global__ __launch_bounds__(256) void gate_norm_kernel(const float* __restrict__ yb,
        const float* __restrict__ zx, const float* __restrict__ norm_w,
        float* __restrict__ gn) {
    const int bl = blockIdx.x;
    const int tid = threadIdx.x;
    const float* yrow = yb + (size_t)bl * DIN;
    const float* zrow = zx + (size_t)bl * DTOT + OFF_Z;
    float g[8];
    float ss = 0.f;
    #pragma unroll
    for (int i = 0; i < 8; ++i) {
        const int c = tid + i * 256;
        const float yv = yrow[c];
        const float zv = zrow[c];
        const float sg = 1.f / (1.f + expf(-zv));
        const float gv = yv * zv * sg;
        g[i] = gv;
        ss += gv * gv;
    }
    #pragma unroll
    for (int k = 1; k < 64; k <<= 1) ss += __shfl_xor(ss, k);
    __shared__ float wsum[4];
    if ((tid & 63) == 0) wsum[tid >> 6] = ss;
    __syncthreads();
    ss = wsum[0] + wsum[1] + wsum[2] + wsum[3];
    const float sc = rsqrtf(ss * (1.f / 2048.f) + 1e-5f);
    #pragma unroll
    for (int i = 0; i < 8; ++i) {
        const int c = tid + i * 256;
        gn[(size_t)bl * DIN + c] = g[i] * sc * norm_w[c];
    }
}

// ---------------------------------------------------------------------------
extern "C" void kernel_launch(void* const* d_in, const int* in_sizes, int n_in,
                              void* d_out, int out_size, void* d_ws, size_t ws_size,
                              hipStream_t stream) {
    const float* u          = (const float*)d_in[0];
    const float* in_proj_w  = (const float*)d_in[1];
    const float* dt_bias    = (const float*)d_in[2];
    const float* A_log      = (const float*)d_in[3];
    const float* Dp         = (const float*)d_in[4];
    const float* B_norm_w   = (const float*)d_in[5];
    const float* C_norm_w   = (const float*)d_in[6];
    const float* B_bias     = (const float*)d_in[7];
    const float* C_bias     = (const float*)d_in[8];
    const float* norm_w     = (const float*)d_in[9];
    const float* out_proj_w = (const float*)d_in[10];
    float* out = (float*)d_out;

    float* p = (float*)d_ws;
    float* zx    = p; p += (size_t)ROWS * DTOT;
    float* th_cs = p; p += (size_t)ROWS * 1024;
    float* Brot  = p; p += (size_t)ROWS * 2048;
    float* Crot  = p; p += (size_t)ROWS * 2048;
    float* Bg    = p; p += (size_t)ROWS * 64;
    float* Cg    = p; p += (size_t)ROWS * 64;
    float4* abg4 = (float4*)p; p += (size_t)ROWS * NH * 4;
    float* yb    = p; p += (size_t)ROWS * 2048;
    float* gn    = Brot;   // reuse: Brot dead after scan

    // 1a. z/x block via bf16 MFMA: zx[:, 0:4096]
    mfma_gemm_zx<<<dim3(NZX / 128, ROWS / 128), 256, 0, stream>>>(u, in_proj_w, zx);
    // 1b. sensitive columns via split-bf16 3-pass MFMA: zx[:, 4096:5312]
    mfma_gemm_rem3<<<dim3(NREM / 64, ROWS / 128), 256, 0, stream>>>(
        u, in_proj_w + (size_t)NZX * DMODEL, zx + NZX);
    // 2. per-row prep
    prep_kernel<<<ROWS, 64, 0, stream>>>(zx, dt_bias, A_log, B_norm_w, C_norm_w,
                                         Bg, Cg, abg4);
    // 3. cumsum of theta over L
    cumsum_kernel<<<BB * NH, 256, 0, stream>>>(zx, th_cs);
    // 4. rotary on B/C
    rot_kernel<<<(ROWS * 1024) / 256, 256, 0, stream>>>(th_cs, Bg, Cg, B_bias, C_bias,
                                                        Brot, Crot);
    // 5. sequential scan over L
    scan_kernel<<<BB * NH * 4, 256, 0, stream>>>(zx, Brot, Crot, abg4, Dp, yb);
    // 6. gate + RMS norm
    gate_norm_kernel<<<ROWS, 256, 0, stream>>>(yb, zx, norm_w, gn);
    // 7. out = gn @ out_proj_w^T  via bf16 MFMA (128x64 tile, 256 blocks)
    mfma_gemm_out<<<dim3(DMODEL / 64, ROWS / 128), 256, 0, stream>>>(
        gn, out_proj_w, out, DIN, DMODEL);
}